// Round 2
// baseline (234.223 us; speedup 1.0000x reference)
//
#include <hip/hip_runtime.h>
#include <math.h>

#define NK 256
#define NT 128
#define NC 32
#define ND 10
#define NSPK 1000000
#define NPAIR 55            // i<=j pairs for D=10
#define CSTRIDE 68          // 55 quad + 10 lin + 1 const, padded to 68
#define LOG2PI 1.8378770664093453f
#define SPIKE_BLOCKS ((NSPK + 255) / 256)

// ws layout:
//   [0, 8)         double accumulator
//   [8, 12)        uint completion counter
//   [256, ~9K)     float coefs[NC][CSTRIDE]
//   [16384, +4MB)  float pisT[NK*NT][NC]   (log_pis transposed: contiguous in c)

// ---------------- Fused prep: block 0 = coefs, block 1 = scalar terms,
// ----------------              blocks 2..129 = log-softmax pis table ---------
__global__ void prep_kernel(const float* __restrict__ y,
                            const float* __restrict__ means,
                            const float* __restrict__ covs,
                            const float* __restrict__ b_mu,
                            const float* __restrict__ b_ls,
                            const float* __restrict__ beta_mu,
                            const float* __restrict__ beta_ls,
                            float* __restrict__ coefs,
                            float* __restrict__ pisT,
                            double* __restrict__ acc) {
  int blk = blockIdx.x;
  int tid = threadIdx.x;

  if (blk == 0) {
    // ---- per-component quadratic-form coefficients (1 thread / component) --
    int c = tid;
    if (c >= NC) return;

    float A[ND][ND];
    #pragma unroll
    for (int i = 0; i < ND; ++i)
      #pragma unroll
      for (int j = 0; j < ND; ++j)
        A[i][j] = covs[c * ND * ND + i * ND + j];

    // Cholesky A = L L^T
    float L[ND][ND];
    #pragma unroll
    for (int i = 0; i < ND; ++i)
      #pragma unroll
      for (int j = 0; j < ND; ++j) L[i][j] = 0.f;

    float logdet = 0.f;
    #pragma unroll
    for (int j = 0; j < ND; ++j) {
      float sum = A[j][j];
      #pragma unroll
      for (int k = 0; k < ND; ++k) if (k < j) sum -= L[j][k] * L[j][k];
      float ljj = sqrtf(sum);
      L[j][j] = ljj;
      logdet += 2.f * __logf(ljj);
      float inv = 1.f / ljj;
      #pragma unroll
      for (int i = 0; i < ND; ++i) {
        if (i > j) {
          float s2 = A[i][j];
          #pragma unroll
          for (int k = 0; k < ND; ++k) if (k < j) s2 -= L[i][k] * L[j][k];
          L[i][j] = s2 * inv;
        }
      }
    }

    // invert lower-triangular L -> Li
    float Li[ND][ND];
    #pragma unroll
    for (int i = 0; i < ND; ++i)
      #pragma unroll
      for (int j = 0; j < ND; ++j) Li[i][j] = 0.f;
    #pragma unroll
    for (int j = 0; j < ND; ++j) {
      Li[j][j] = 1.f / L[j][j];
      #pragma unroll
      for (int i = 0; i < ND; ++i) {
        if (i > j) {
          float s2 = 0.f;
          #pragma unroll
          for (int k = 0; k < ND; ++k) if (k >= j && k < i) s2 += L[i][k] * Li[k][j];
          Li[i][j] = -s2 / L[i][i];
        }
      }
    }

    // P = Li^T Li (precision)
    float P[ND][ND];
    #pragma unroll
    for (int i = 0; i < ND; ++i)
      #pragma unroll
      for (int j = 0; j < ND; ++j) {
        if (j >= i) {
          float s2 = 0.f;
          #pragma unroll
          for (int k = 0; k < ND; ++k) if (k >= j) s2 += Li[k][i] * Li[k][j];
          P[i][j] = s2;
        }
      }
    #pragma unroll
    for (int i = 0; i < ND; ++i)
      #pragma unroll
      for (int j = 0; j < ND; ++j) if (j < i) P[i][j] = P[j][i];

    float mu[ND], q[ND];
    #pragma unroll
    for (int i = 0; i < ND; ++i) mu[i] = means[c * ND + i];
    float muPmu = 0.f;
    #pragma unroll
    for (int i = 0; i < ND; ++i) {
      float a2 = 0.f;
      #pragma unroll
      for (int j = 0; j < ND; ++j) a2 += P[i][j] * mu[j];
      q[i] = a2;
      muPmu += mu[i] * a2;
    }
    float cst = -0.5f * ((float)ND * LOG2PI + logdet + muPmu);

    float* out = coefs + c * CSTRIDE;
    int idx = 0;
    #pragma unroll
    for (int i = 0; i < ND; ++i)
      #pragma unroll
      for (int j = 0; j < ND; ++j)
        if (j >= i) out[idx++] = (i == j) ? -0.5f * P[i][i] : -P[i][j];
    #pragma unroll
    for (int i = 0; i < ND; ++i) out[NPAIR + i] = q[i];
    out[NPAIR + ND] = cst;   // index 65
    out[66] = 0.f;
    out[67] = 0.f;

  } else if (blk == 1) {
    // ---- prior - q scalar terms -> acc -----------------------------------
    float local = 0.f;
    for (int i = tid; i < NC; i += 256)
      local += fmaf(-0.5f * b_mu[i], b_mu[i], b_ls[i]);
    for (int i = tid; i < NC * NT; i += 256)
      local += fmaf(-0.5f * beta_mu[i], beta_mu[i], beta_ls[i]);
    #pragma unroll
    for (int off = 32; off > 0; off >>= 1) local += __shfl_down(local, off);
    __shared__ float red[4];
    if ((tid & 63) == 0) red[tid >> 6] = local;
    __syncthreads();
    if (tid == 0) atomicAdd(acc, (double)(red[0] + red[1] + red[2] + red[3]));

  } else {
    // ---- log-softmax pis table, transposed [k*NT+t][c] -------------------
    int id = (blk - 2) * 256 + tid;          // id = k*NT + t
    int t = id & (NT - 1);
    float yv = y[id];
    float v[NC];
    float m = -1e30f;
    #pragma unroll
    for (int c = 0; c < NC; ++c) {
      v[c] = fmaf(beta_mu[c * NT + t], yv, b_mu[c]);
      m = fmaxf(m, v[c]);
    }
    float ssum = 0.f;
    #pragma unroll
    for (int c = 0; c < NC; ++c) ssum += __expf(v[c] - m);
    float lz = m + __logf(ssum);
    float* outp = pisT + (size_t)id * NC;
    #pragma unroll
    for (int c = 0; c < NC; ++c) outp[c] = v[c] - lz;
  }
}

// ---------------- Main: per-spike logsumexp + self-finalize ------------------
__global__ __launch_bounds__(256, 4)
void spike_kernel(const float* __restrict__ s,
                  const int* __restrict__ ks,
                  const int* __restrict__ ts,
                  const float* __restrict__ coefs,
                  const float* __restrict__ pisT,
                  double* __restrict__ acc,
                  unsigned int* __restrict__ counter,
                  float* __restrict__ out) {
  int n = blockIdx.x * 256 + threadIdx.x;
  float lse = 0.f;
  if (n < NSPK) {
    const float2* srow = (const float2*)(s + (size_t)n * ND);
    float sv[ND];
    #pragma unroll
    for (int i = 0; i < 5; ++i) {
      float2 v2 = srow[i];
      sv[2 * i] = v2.x;
      sv[2 * i + 1] = v2.y;
    }
    int k = ks[n], t = ts[n];
    const float4* lp4 = (const float4*)(pisT + (size_t)(k * NT + t) * NC);
    float lp[NC];
    #pragma unroll
    for (int g = 0; g < NC / 4; ++g) {
      float4 v4 = lp4[g];
      lp[4 * g + 0] = v4.x; lp[4 * g + 1] = v4.y;
      lp[4 * g + 2] = v4.z; lp[4 * g + 3] = v4.w;
    }

    // pass 1: logits for all 32 components (nested form, no feat[] array)
    float vv[NC];
    #pragma unroll
    for (int c = 0; c < NC; ++c) {
      const float* __restrict__ w = coefs + c * CSTRIDE;  // wave-uniform
      float a = w[NPAIR + ND];                            // const term
      int idx = 0;
      #pragma unroll
      for (int i = 0; i < ND; ++i) {
        float inner = w[NPAIR + i];                       // q_i
        #pragma unroll
        for (int j = i; j < ND; ++j) {
          inner = fmaf(w[idx], sv[j], inner);
          ++idx;
        }
        a = fmaf(sv[i], inner, a);
      }
      vv[c] = a + lp[c];
    }

    // pass 2: two-pass logsumexp (independent exps, no select chain)
    float m = vv[0];
    #pragma unroll
    for (int c = 1; c < NC; ++c) m = fmaxf(m, vv[c]);
    float ssum = 0.f;
    #pragma unroll
    for (int c = 0; c < NC; ++c) ssum += __expf(vv[c] - m);
    lse = m + __logf(ssum);
  }

  // block reduction -> one fp64 atomic per block
  #pragma unroll
  for (int off = 32; off > 0; off >>= 1) lse += __shfl_down(lse, off);
  __shared__ float red[4];
  if ((threadIdx.x & 63) == 0) red[threadIdx.x >> 6] = lse;
  __syncthreads();
  if (threadIdx.x == 0) {
    atomicAdd(acc, (double)(red[0] + red[1] + red[2] + red[3]));
    __threadfence();
    unsigned int old = atomicAdd(counter, 1u);
    if (old == SPIKE_BLOCKS - 1) {
      __threadfence();
      double v = atomicAdd(acc, 0.0);   // coherent device-scope read
      out[0] = (float)v;
    }
  }
}

extern "C" void kernel_launch(void* const* d_in, const int* in_sizes, int n_in,
                              void* d_out, int out_size, void* d_ws, size_t ws_size,
                              hipStream_t stream) {
  const float* s       = (const float*)d_in[0];
  const float* y       = (const float*)d_in[1];
  const int*   ks      = (const int*)d_in[2];
  const int*   ts      = (const int*)d_in[3];
  const float* means   = (const float*)d_in[4];
  const float* covs    = (const float*)d_in[5];
  const float* b_mu    = (const float*)d_in[6];
  const float* b_ls    = (const float*)d_in[7];
  const float* beta_mu = (const float*)d_in[8];
  const float* beta_ls = (const float*)d_in[9];
  float* out = (float*)d_out;

  char* ws = (char*)d_ws;
  double* acc           = (double*)ws;
  unsigned int* counter = (unsigned int*)(ws + 8);
  float* coefs          = (float*)(ws + 256);
  float* pisT           = (float*)(ws + 16384);

  hipMemsetAsync(ws, 0, 128, stream);
  prep_kernel<<<2 + (NK * NT) / 256, 256, 0, stream>>>(
      y, means, covs, b_mu, b_ls, beta_mu, beta_ls, coefs, pisT, acc);
  spike_kernel<<<SPIKE_BLOCKS, 256, 0, stream>>>(
      s, ks, ts, coefs, pisT, acc, counter, out);
}

// Round 3
// 210.843 us; speedup vs baseline: 1.1109x; 1.1109x over previous
//
#include <hip/hip_runtime.h>
#include <hip/hip_bf16.h>
#include <math.h>

#define NK 256
#define NT 128
#define NC 32
#define ND 10
#define NSPK 1000000
#define LOG2PI 1.8378770664093453f
#define SPIKE_BLOCKS ((NSPK + 255) / 256)   // 3907

#define FSTR 36            // dwords per feature row (32 data + 4 pad, 16B-aligned stride)
#define LSTR 33            // dwords per logits row (conflict-free epilogue reads)
#define WROWS 64           // 32 hi rows + 32 lo rows
#define LDS_FEAT_DW (256 * FSTR)       // 9216
#define LDS_W_DW    (WROWS * FSTR)     // 2304

typedef __attribute__((ext_vector_type(8))) short short8;
typedef __attribute__((ext_vector_type(4))) float floatx4;
typedef __attribute__((ext_vector_type(4))) int intx4;

union FragCvt { intx4 i; short8 s; };

// ws layout:
//   [0,8)      double acc
//   [8,12)     uint counter
//   [64,320)   float cpack[64]  : [c]=cst_c, [32+c]=w99_c
//   [1024,..)  int wt[64][36]   : bf16-pair-packed W, rows 0..31 hi, 32..63 lo
//   [16384,..) float pisT[NK*NT][32]

__device__ inline unsigned pack_bf16(float a, float b) {
  __hip_bfloat16 ha = __float2bfloat16(a), hb = __float2bfloat16(b);
  unsigned short ua, ub;
  __builtin_memcpy(&ua, &ha, 2);
  __builtin_memcpy(&ub, &hb, 2);
  return (unsigned)ua | ((unsigned)ub << 16);
}

// ============================ PREP =========================================
__global__ void prep_kernel(const float* __restrict__ y,
                            const float* __restrict__ means,
                            const float* __restrict__ covs,
                            const float* __restrict__ b_mu,
                            const float* __restrict__ b_ls,
                            const float* __restrict__ beta_mu,
                            const float* __restrict__ beta_ls,
                            int* __restrict__ wt,
                            float* __restrict__ cpack,
                            float* __restrict__ pisT,
                            double* __restrict__ acc,
                            unsigned int* __restrict__ counter) {
  int blk = blockIdx.x;
  int tid = threadIdx.x;

  if (blk == 0) {
    // ---- per-component coefficients, fully IN-PLACE (no scratch spill) ----
    int c = tid;
    if (c >= NC) return;

    float M[ND][ND];
    #pragma unroll
    for (int i = 0; i < ND; ++i)
      #pragma unroll
      for (int j = 0; j < ND; ++j)
        M[i][j] = covs[c * ND * ND + i * ND + j];

    // Cholesky, lower triangle in place
    float logdet = 0.f;
    #pragma unroll
    for (int j = 0; j < ND; ++j) {
      float d = M[j][j];
      #pragma unroll
      for (int k = 0; k < ND; ++k) if (k < j) d -= M[j][k] * M[j][k];
      float sq = sqrtf(d);
      M[j][j] = sq;
      logdet += 2.f * __logf(sq);
      float inv = 1.f / sq;
      #pragma unroll
      for (int i = 0; i < ND; ++i) {
        if (i > j) {
          float s2 = M[i][j];
          #pragma unroll
          for (int k = 0; k < ND; ++k) if (k < j) s2 -= M[i][k] * M[j][k];
          M[i][j] = s2 * inv;
        }
      }
    }

    // invert lower triangle in place: M(lower) := L^-1
    #pragma unroll
    for (int j = 0; j < ND; ++j) {
      M[j][j] = 1.f / M[j][j];
      #pragma unroll
      for (int i = 0; i < ND; ++i) {
        if (i > j) {
          float s2 = 0.f;
          #pragma unroll
          for (int k = 0; k < ND; ++k) if (k >= j && k < i) s2 += M[i][k] * M[k][j];
          M[i][j] = -s2 / M[i][i];
        }
      }
    }

    // P = Li^T Li : off-diag -> upper triangle of M, diag -> pd[]
    float pd[ND];
    #pragma unroll
    for (int i = 0; i < ND; ++i) {
      #pragma unroll
      for (int jj = 0; jj < ND; ++jj) {
        if (jj >= i) {
          float s2 = 0.f;
          #pragma unroll
          for (int k = 0; k < ND; ++k) if (k >= jj) s2 += M[k][i] * M[k][jj];
          if (jj > i) M[i][jj] = s2;
          else pd[i] = s2;
        }
      }
    }

    float mu[ND], q[ND];
    #pragma unroll
    for (int i = 0; i < ND; ++i) mu[i] = means[c * ND + i];
    float muPmu = 0.f;
    #pragma unroll
    for (int i = 0; i < ND; ++i) {
      float a2 = pd[i] * mu[i];
      #pragma unroll
      for (int j = 0; j < ND; ++j) {
        if (j < i) a2 += M[j][i] * mu[j];
        if (j > i) a2 += M[i][j] * mu[j];
      }
      q[i] = a2;
      muPmu += mu[i] * a2;
    }
    float cst = -0.5f * ((float)ND * LOG2PI + logdet + muPmu);

    // K=64 coefficient vector: 54 pairs (all i<=j except (9,9)) + 10 linear
    float wv[64];
    int p = 0;
    #pragma unroll
    for (int i = 0; i < ND; ++i)
      #pragma unroll
      for (int j = 0; j < ND; ++j)
        if (j >= i && !(i == 9 && j == 9))
          wv[p++] = (i == j) ? -0.5f * pd[i] : -M[i][j];
    #pragma unroll
    for (int i = 0; i < ND; ++i) wv[54 + i] = q[i];

    // hi/lo split, bf16-pair pack, store rows c (hi) and 32+c (lo)
    #pragma unroll
    for (int j = 0; j < 32; ++j) {
      float a = wv[2 * j], b = wv[2 * j + 1];
      float ah = __bfloat162float(__float2bfloat16(a));
      float bh = __bfloat162float(__float2bfloat16(b));
      wt[c * FSTR + j] = pack_bf16(ah, bh);
      wt[(32 + c) * FSTR + j] = pack_bf16(a - ah, b - bh);
    }
    #pragma unroll
    for (int j = 32; j < FSTR; ++j) {
      wt[c * FSTR + j] = 0;
      wt[(32 + c) * FSTR + j] = 0;
    }
    cpack[c] = cst;
    cpack[32 + c] = -0.5f * pd[9];   // w99

  } else if (blk == 1) {
    // ---- prior - q scalar terms -> plain-store acc, init counter ----------
    float local = 0.f;
    for (int i = tid; i < NC; i += 256)
      local += fmaf(-0.5f * b_mu[i], b_mu[i], b_ls[i]);
    for (int i = tid; i < NC * NT; i += 256)
      local += fmaf(-0.5f * beta_mu[i], beta_mu[i], beta_ls[i]);
    #pragma unroll
    for (int off = 32; off > 0; off >>= 1) local += __shfl_down(local, off);
    __shared__ float red[4];
    if ((tid & 63) == 0) red[tid >> 6] = local;
    __syncthreads();
    if (tid == 0) {
      acc[0] = (double)(red[0] + red[1] + red[2] + red[3]);
      counter[0] = 0u;
    }

  } else {
    // ---- log-softmax pis table, [k*NT+t][c] contiguous --------------------
    int id = (blk - 2) * 256 + tid;          // id = k*NT + t
    int t = id & (NT - 1);
    float yv = y[id];
    float v[NC];
    float m = -1e30f;
    #pragma unroll
    for (int c = 0; c < NC; ++c) {
      v[c] = fmaf(beta_mu[c * NT + t], yv, b_mu[c]);
      m = fmaxf(m, v[c]);
    }
    float ssum = 0.f;
    #pragma unroll
    for (int c = 0; c < NC; ++c) ssum += __expf(v[c] - m);
    float lz = m + __logf(ssum);
    float* outp = pisT + (size_t)id * NC;
    #pragma unroll
    for (int c = 0; c < NC; ++c) outp[c] = v[c] - lz;
  }
}

// ============================ MAIN (MFMA) ==================================
__global__ __launch_bounds__(256, 2)
void spike_kernel(const float* __restrict__ s,
                  const int* __restrict__ ks,
                  const int* __restrict__ ts,
                  const int* __restrict__ wt,
                  const float* __restrict__ cpack,
                  const float* __restrict__ pisT,
                  double* __restrict__ acc,
                  unsigned int* __restrict__ counter,
                  float* __restrict__ out) {
  __shared__ int lds[LDS_FEAT_DW + LDS_W_DW];   // 46.1 KB

  int tid = threadIdx.x;
  int n = blockIdx.x * 256 + tid;
  int nc = n < NSPK ? n : (NSPK - 1);

  // issue gathers early (consumed ~2000 cyc later in epilogue)
  int kk_ = ks[nc], tt_ = ts[nc];
  const float4* lpp = (const float4*)(pisT + (size_t)(kk_ * NT + tt_) * NC);
  float4 lpv[8];
  #pragma unroll
  for (int i = 0; i < 8; ++i) lpv[i] = lpp[i];

  // load s row, build K=64 feature vector, pack to bf16, stage to LDS
  const float2* srow = (const float2*)(s + (size_t)nc * ND);
  float sv[ND];
  #pragma unroll
  for (int i = 0; i < 5; ++i) {
    float2 v2 = srow[i];
    sv[2 * i] = v2.x;
    sv[2 * i + 1] = v2.y;
  }
  {
    float fv[64];
    int p = 0;
    #pragma unroll
    for (int i = 0; i < ND; ++i)
      #pragma unroll
      for (int j = 0; j < ND; ++j)
        if (j >= i && !(i == 9 && j == 9)) fv[p++] = sv[i] * sv[j];
    #pragma unroll
    for (int i = 0; i < ND; ++i) fv[54 + i] = sv[i];

    int rb = tid * FSTR;
    #pragma unroll
    for (int ch = 0; ch < 8; ++ch) {
      intx4 v;
      v.x = (int)pack_bf16(fv[8 * ch + 0], fv[8 * ch + 1]);
      v.y = (int)pack_bf16(fv[8 * ch + 2], fv[8 * ch + 3]);
      v.z = (int)pack_bf16(fv[8 * ch + 4], fv[8 * ch + 5]);
      v.w = (int)pack_bf16(fv[8 * ch + 6], fv[8 * ch + 7]);
      *(intx4*)&lds[rb + ch * 4] = v;
    }
  }
  // stage W (hi+lo) into LDS
  for (int i = tid; i < LDS_W_DW; i += 256) lds[LDS_FEAT_DW + i] = wt[i];
  __syncthreads();

  // MFMA: D[spike][c] = F x (Whi + Wlo)
  int wv_ = tid >> 6, L = tid & 63;
  int r = L & 15, q = L >> 4;

  FragCvt bf[2][2][2];   // [h][nt][kstep]
  #pragma unroll
  for (int h = 0; h < 2; ++h)
    #pragma unroll
    for (int nt = 0; nt < 2; ++nt)
      #pragma unroll
      for (int ks2 = 0; ks2 < 2; ++ks2)
        bf[h][nt][ks2].i =
            *(const intx4*)&lds[LDS_FEAT_DW + (h * 32 + nt * 16 + r) * FSTR +
                                ks2 * 16 + q * 4];

  floatx4 accf[4][2];
  #pragma unroll
  for (int mt = 0; mt < 4; ++mt)
    #pragma unroll
    for (int nt = 0; nt < 2; ++nt)
      accf[mt][nt] = (floatx4){0.f, 0.f, 0.f, 0.f};

  #pragma unroll
  for (int mt = 0; mt < 4; ++mt) {
    #pragma unroll
    for (int ks2 = 0; ks2 < 2; ++ks2) {
      FragCvt a;
      a.i = *(const intx4*)&lds[(wv_ * 64 + mt * 16 + r) * FSTR + ks2 * 16 + q * 4];
      #pragma unroll
      for (int nt = 0; nt < 2; ++nt) {
        accf[mt][nt] = __builtin_amdgcn_mfma_f32_16x16x32_bf16(
            a.s, bf[0][nt][ks2].s, accf[mt][nt], 0, 0, 0);
        accf[mt][nt] = __builtin_amdgcn_mfma_f32_16x16x32_bf16(
            a.s, bf[1][nt][ks2].s, accf[mt][nt], 0, 0, 0);
      }
    }
  }
  __syncthreads();   // all feat reads done -> safe to overwrite with logits

  // scatter C-frags to LDS logits[spike][c]  (row = q*4+reg, col = r)
  #pragma unroll
  for (int mt = 0; mt < 4; ++mt)
    #pragma unroll
    for (int nt = 0; nt < 2; ++nt)
      #pragma unroll
      for (int rr = 0; rr < 4; ++rr) {
        int srow_ = wv_ * 64 + mt * 16 + q * 4 + rr;
        lds[srow_ * LSTR + nt * 16 + r] = __float_as_int(accf[mt][nt][rr]);
      }
  __syncthreads();

  // epilogue: logits += lp + cst + w99*s9^2 ; logsumexp ; reduce
  float lse = 0.f;
  {
    float lp[32];
    #pragma unroll
    for (int i = 0; i < 8; ++i) {
      lp[4 * i + 0] = lpv[i].x; lp[4 * i + 1] = lpv[i].y;
      lp[4 * i + 2] = lpv[i].z; lp[4 * i + 3] = lpv[i].w;
    }
    float s9sq = sv[9] * sv[9];
    int base = tid * LSTR;
    float lg[32];
    #pragma unroll
    for (int c = 0; c < 32; ++c)
      lg[c] = __int_as_float(lds[base + c]) + lp[c] +
              fmaf(cpack[32 + c], s9sq, cpack[c]);

    float m = lg[0];
    #pragma unroll
    for (int c = 1; c < 32; ++c) m = fmaxf(m, lg[c]);
    float ssum = 0.f;
    #pragma unroll
    for (int c = 0; c < 32; ++c) ssum += __expf(lg[c] - m);
    lse = (n < NSPK) ? (m + __logf(ssum)) : 0.f;
  }

  #pragma unroll
  for (int off = 32; off > 0; off >>= 1) lse += __shfl_down(lse, off);
  __shared__ float red[4];
  if ((tid & 63) == 0) red[tid >> 6] = lse;
  __syncthreads();
  if (tid == 0) {
    atomicAdd(acc, (double)(red[0] + red[1] + red[2] + red[3]));
    __threadfence();
    unsigned int old = atomicAdd(counter, 1u);
    if (old == SPIKE_BLOCKS - 1) {
      __threadfence();
      double v = atomicAdd(acc, 0.0);
      out[0] = (float)v;
    }
  }
}

extern "C" void kernel_launch(void* const* d_in, const int* in_sizes, int n_in,
                              void* d_out, int out_size, void* d_ws, size_t ws_size,
                              hipStream_t stream) {
  const float* s       = (const float*)d_in[0];
  const float* y       = (const float*)d_in[1];
  const int*   ks      = (const int*)d_in[2];
  const int*   ts      = (const int*)d_in[3];
  const float* means   = (const float*)d_in[4];
  const float* covs    = (const float*)d_in[5];
  const float* b_mu    = (const float*)d_in[6];
  const float* b_ls    = (const float*)d_in[7];
  const float* beta_mu = (const float*)d_in[8];
  const float* beta_ls = (const float*)d_in[9];
  float* out = (float*)d_out;

  char* ws = (char*)d_ws;
  double* acc           = (double*)ws;
  unsigned int* counter = (unsigned int*)(ws + 8);
  float* cpack          = (float*)(ws + 64);
  int* wt               = (int*)(ws + 1024);
  float* pisT           = (float*)(ws + 16384);

  prep_kernel<<<2 + (NK * NT) / 256, 256, 0, stream>>>(
      y, means, covs, b_mu, b_ls, beta_mu, beta_ls, wt, cpack, pisT, acc, counter);
  spike_kernel<<<SPIKE_BLOCKS, 256, 0, stream>>>(
      s, ks, ts, wt, cpack, pisT, acc, counter, out);
}

// Round 4
// 168.032 us; speedup vs baseline: 1.3939x; 1.2548x over previous
//
#include <hip/hip_runtime.h>
#include <hip/hip_bf16.h>
#include <math.h>

#define NK 256
#define NT 128
#define NC 32
#define ND 10
#define NSPK 1000000
#define LOG2PI 1.8378770664093453f
#define NCHUNK ((NSPK + 255) / 256)   // 3907
#define GRID 1024                     // 4 blocks/CU x 256 CUs, all co-resident

#define FSTR 36            // dwords per LDS row (32 data + 4 pad), 144B = 16B-aligned
#define LDS_DW (256 * FSTR)           // 9216 dw = 36 KB, shared by feat & logits

typedef __attribute__((ext_vector_type(8))) short short8;
typedef __attribute__((ext_vector_type(4))) float floatx4;
typedef __attribute__((ext_vector_type(4))) int intx4;

union FragCvt { intx4 i; short8 s; };

// ws layout:
//   [0,8)      double acc
//   [8,12)     uint counter
//   [64,320)   float cpack[64] : [c]=cst_c, [32+c]=w99_c
//   [1024,..)  int wt[64][32]  : bf16-pair-packed W, rows 0..31 hi, 32..63 lo
//   [16384,..) float pisT[NK*NT][32]

__device__ inline unsigned pack_bf16(float a, float b) {
  __hip_bfloat16 ha = __float2bfloat16(a), hb = __float2bfloat16(b);
  unsigned short ua, ub;
  __builtin_memcpy(&ua, &ha, 2);
  __builtin_memcpy(&ub, &hb, 2);
  return (unsigned)ua | ((unsigned)ub << 16);
}

// ============================ PREP =========================================
__global__ void prep_kernel(const float* __restrict__ y,
                            const float* __restrict__ means,
                            const float* __restrict__ covs,
                            const float* __restrict__ b_mu,
                            const float* __restrict__ b_ls,
                            const float* __restrict__ beta_mu,
                            const float* __restrict__ beta_ls,
                            int* __restrict__ wt,
                            float* __restrict__ cpack,
                            float* __restrict__ pisT,
                            double* __restrict__ acc,
                            unsigned int* __restrict__ counter) {
  int blk = blockIdx.x;
  int tid = threadIdx.x;

  if (blk == 0) {
    // ---- per-component coefficients, fully in place (no scratch) ----------
    int c = tid;
    if (c >= NC) return;

    float M[ND][ND];
    #pragma unroll
    for (int i = 0; i < ND; ++i)
      #pragma unroll
      for (int j = 0; j < ND; ++j)
        M[i][j] = covs[c * ND * ND + i * ND + j];

    // Cholesky, lower triangle in place
    float logdet = 0.f;
    #pragma unroll
    for (int j = 0; j < ND; ++j) {
      float d = M[j][j];
      #pragma unroll
      for (int k = 0; k < ND; ++k) if (k < j) d -= M[j][k] * M[j][k];
      float sq = sqrtf(d);
      M[j][j] = sq;
      logdet += 2.f * __logf(sq);
      float inv = 1.f / sq;
      #pragma unroll
      for (int i = 0; i < ND; ++i) {
        if (i > j) {
          float s2 = M[i][j];
          #pragma unroll
          for (int k = 0; k < ND; ++k) if (k < j) s2 -= M[i][k] * M[j][k];
          M[i][j] = s2 * inv;
        }
      }
    }

    // invert lower triangle in place: M(lower) := L^-1
    #pragma unroll
    for (int j = 0; j < ND; ++j) {
      M[j][j] = 1.f / M[j][j];
      #pragma unroll
      for (int i = 0; i < ND; ++i) {
        if (i > j) {
          float s2 = 0.f;
          #pragma unroll
          for (int k = 0; k < ND; ++k) if (k >= j && k < i) s2 += M[i][k] * M[k][j];
          M[i][j] = -s2 / M[i][i];
        }
      }
    }

    // P = Li^T Li : off-diag -> upper triangle of M, diag -> pd[]
    float pd[ND];
    #pragma unroll
    for (int i = 0; i < ND; ++i) {
      #pragma unroll
      for (int jj = 0; jj < ND; ++jj) {
        if (jj >= i) {
          float s2 = 0.f;
          #pragma unroll
          for (int k = 0; k < ND; ++k) if (k >= jj) s2 += M[k][i] * M[k][jj];
          if (jj > i) M[i][jj] = s2;
          else pd[i] = s2;
        }
      }
    }

    float mu[ND], q[ND];
    #pragma unroll
    for (int i = 0; i < ND; ++i) mu[i] = means[c * ND + i];
    float muPmu = 0.f;
    #pragma unroll
    for (int i = 0; i < ND; ++i) {
      float a2 = pd[i] * mu[i];
      #pragma unroll
      for (int j = 0; j < ND; ++j) {
        if (j < i) a2 += M[j][i] * mu[j];
        if (j > i) a2 += M[i][j] * mu[j];
      }
      q[i] = a2;
      muPmu += mu[i] * a2;
    }
    float cst = -0.5f * ((float)ND * LOG2PI + logdet + muPmu);

    // K=64 coefficient vector: 54 pairs (all i<=j except (9,9)) + 10 linear
    float wv[64];
    int p = 0;
    #pragma unroll
    for (int i = 0; i < ND; ++i)
      #pragma unroll
      for (int j = 0; j < ND; ++j)
        if (j >= i && !(i == 9 && j == 9))
          wv[p++] = (i == j) ? -0.5f * pd[i] : -M[i][j];
    #pragma unroll
    for (int i = 0; i < ND; ++i) wv[54 + i] = q[i];

    // hi/lo split, bf16-pair pack; packed rows of 32 dwords (128B)
    #pragma unroll
    for (int j = 0; j < 32; ++j) {
      float a = wv[2 * j], b = wv[2 * j + 1];
      float ah = __bfloat162float(__float2bfloat16(a));
      float bh = __bfloat162float(__float2bfloat16(b));
      wt[c * 32 + j] = (int)pack_bf16(ah, bh);
      wt[(32 + c) * 32 + j] = (int)pack_bf16(a - ah, b - bh);
    }
    cpack[c] = cst;
    cpack[32 + c] = -0.5f * pd[9];   // w99

  } else if (blk == 1) {
    // ---- prior - q scalar terms -> plain-store acc, init counter ----------
    float local = 0.f;
    for (int i = tid; i < NC; i += 256)
      local += fmaf(-0.5f * b_mu[i], b_mu[i], b_ls[i]);
    for (int i = tid; i < NC * NT; i += 256)
      local += fmaf(-0.5f * beta_mu[i], beta_mu[i], beta_ls[i]);
    #pragma unroll
    for (int off = 32; off > 0; off >>= 1) local += __shfl_down(local, off);
    __shared__ float red[4];
    if ((tid & 63) == 0) red[tid >> 6] = local;
    __syncthreads();
    if (tid == 0) {
      acc[0] = (double)(red[0] + red[1] + red[2] + red[3]);
      counter[0] = 0u;
    }

  } else {
    // ---- log-softmax pis table, [k*NT+t][c] contiguous --------------------
    int id = (blk - 2) * 256 + tid;          // id = k*NT + t
    int t = id & (NT - 1);
    float yv = y[id];
    float v[NC];
    float m = -1e30f;
    #pragma unroll
    for (int c = 0; c < NC; ++c) {
      v[c] = fmaf(beta_mu[c * NT + t], yv, b_mu[c]);
      m = fmaxf(m, v[c]);
    }
    float ssum = 0.f;
    #pragma unroll
    for (int c = 0; c < NC; ++c) ssum += __expf(v[c] - m);
    float lz = m + __logf(ssum);
    float* outp = pisT + (size_t)id * NC;
    #pragma unroll
    for (int c = 0; c < NC; ++c) outp[c] = v[c] - lz;
  }
}

// ============================ MAIN (persistent MFMA) =======================
__global__ __launch_bounds__(256, 4)
void spike_kernel(const float* __restrict__ s,
                  const int* __restrict__ ks,
                  const int* __restrict__ ts,
                  const int* __restrict__ wt,
                  const float* __restrict__ cpack,
                  const float* __restrict__ pisT,
                  double* __restrict__ acc,
                  unsigned int* __restrict__ counter,
                  float* __restrict__ out) {
  __shared__ int lds[LDS_DW];        // 36 KB: feat (stride 36), then logits (stride 36)
  __shared__ float red[4];

  int tid = threadIdx.x;
  int wv_ = tid >> 6, L = tid & 63;
  int r = L & 15, q = L >> 4;

  // B-frags (W hi+lo) from global -> registers, once per block
  FragCvt bf[2][2][2];   // [h][nt][kstep]
  #pragma unroll
  for (int h = 0; h < 2; ++h)
    #pragma unroll
    for (int nt = 0; nt < 2; ++nt)
      #pragma unroll
      for (int ks2 = 0; ks2 < 2; ++ks2)
        bf[h][nt][ks2].i =
            *(const intx4*)&wt[(h * 32 + nt * 16 + r) * 32 + ks2 * 16 + q * 4];

  float lse_sum = 0.f;

  for (int ci = blockIdx.x; ci < NCHUNK; ci += GRID) {
    int n = ci * 256 + tid;
    int nc = n < NSPK ? n : (NSPK - 1);

    // load s row, build K=64 feature vector
    const float2* srow = (const float2*)(s + (size_t)nc * ND);
    float sv[ND];
    #pragma unroll
    for (int i = 0; i < 5; ++i) {
      float2 v2 = srow[i];
      sv[2 * i] = v2.x;
      sv[2 * i + 1] = v2.y;
    }
    int kk_ = ks[nc], tt_ = ts[nc];

    float fv[64];
    {
      int p = 0;
      #pragma unroll
      for (int i = 0; i < ND; ++i)
        #pragma unroll
        for (int j = 0; j < ND; ++j)
          if (j >= i && !(i == 9 && j == 9)) fv[p++] = sv[i] * sv[j];
      #pragma unroll
      for (int i = 0; i < ND; ++i) fv[54 + i] = sv[i];
    }

    __syncthreads();   // previous iteration's epilogue reads complete
    {
      int rb = tid * FSTR;
      #pragma unroll
      for (int ch = 0; ch < 8; ++ch) {
        intx4 v;
        v.x = (int)pack_bf16(fv[8 * ch + 0], fv[8 * ch + 1]);
        v.y = (int)pack_bf16(fv[8 * ch + 2], fv[8 * ch + 3]);
        v.z = (int)pack_bf16(fv[8 * ch + 4], fv[8 * ch + 5]);
        v.w = (int)pack_bf16(fv[8 * ch + 6], fv[8 * ch + 7]);
        *(intx4*)&lds[rb + ch * 4] = v;
      }
    }
    __syncthreads();

    // MFMA: D[spike][c] = F x (Whi + Wlo)
    floatx4 accf[4][2];
    #pragma unroll
    for (int mt = 0; mt < 4; ++mt)
      #pragma unroll
      for (int nt = 0; nt < 2; ++nt)
        accf[mt][nt] = (floatx4){0.f, 0.f, 0.f, 0.f};

    #pragma unroll
    for (int mt = 0; mt < 4; ++mt) {
      #pragma unroll
      for (int ks2 = 0; ks2 < 2; ++ks2) {
        FragCvt a;
        a.i = *(const intx4*)&lds[(wv_ * 64 + mt * 16 + r) * FSTR + ks2 * 16 + q * 4];
        #pragma unroll
        for (int nt = 0; nt < 2; ++nt) {
          accf[mt][nt] = __builtin_amdgcn_mfma_f32_16x16x32_bf16(
              a.s, bf[0][nt][ks2].s, accf[mt][nt], 0, 0, 0);
          accf[mt][nt] = __builtin_amdgcn_mfma_f32_16x16x32_bf16(
              a.s, bf[1][nt][ks2].s, accf[mt][nt], 0, 0, 0);
        }
      }
    }

    // issue lp gather now (consumed in epilogue, covered by scatter phase)
    const float4* lpp = (const float4*)(pisT + (size_t)(kk_ * NT + tt_) * NC);
    float4 lpv[8];
    #pragma unroll
    for (int i = 0; i < 8; ++i) lpv[i] = lpp[i];

    __syncthreads();   // all feat reads done -> safe to overwrite with logits

    // scatter C-frags to LDS logits[spike][c]  (row = q*4+reg, col = r)
    #pragma unroll
    for (int mt = 0; mt < 4; ++mt)
      #pragma unroll
      for (int nt = 0; nt < 2; ++nt)
        #pragma unroll
        for (int rr = 0; rr < 4; ++rr) {
          int srow_ = wv_ * 64 + mt * 16 + q * 4 + rr;
          lds[srow_ * FSTR + nt * 16 + r] = __float_as_int(accf[mt][nt][rr]);
        }
    __syncthreads();

    // epilogue: logits += lp + cst + w99*s9^2 ; logsumexp
    {
      float lp[32];
      #pragma unroll
      for (int i = 0; i < 8; ++i) {
        lp[4 * i + 0] = lpv[i].x; lp[4 * i + 1] = lpv[i].y;
        lp[4 * i + 2] = lpv[i].z; lp[4 * i + 3] = lpv[i].w;
      }
      float s9sq = sv[9] * sv[9];
      int base = tid * FSTR;
      float lg[32];
      #pragma unroll
      for (int g = 0; g < 8; ++g) {
        intx4 lv = *(const intx4*)&lds[base + g * 4];
        lg[4 * g + 0] = __int_as_float(lv.x);
        lg[4 * g + 1] = __int_as_float(lv.y);
        lg[4 * g + 2] = __int_as_float(lv.z);
        lg[4 * g + 3] = __int_as_float(lv.w);
      }
      #pragma unroll
      for (int c = 0; c < 32; ++c)
        lg[c] += lp[c] + fmaf(cpack[32 + c], s9sq, cpack[c]);

      float m = lg[0];
      #pragma unroll
      for (int c = 1; c < 32; ++c) m = fmaxf(m, lg[c]);
      float ssum = 0.f;
      #pragma unroll
      for (int c = 0; c < 32; ++c) ssum += __expf(lg[c] - m);
      if (n < NSPK) lse_sum += m + __logf(ssum);
    }
  }

  // block reduction -> one fp64 atomic per block
  #pragma unroll
  for (int off = 32; off > 0; off >>= 1) lse_sum += __shfl_down(lse_sum, off);
  if ((tid & 63) == 0) red[tid >> 6] = lse_sum;
  __syncthreads();
  if (tid == 0) {
    atomicAdd(acc, (double)(red[0] + red[1] + red[2] + red[3]));
    __threadfence();
    unsigned int old = atomicAdd(counter, 1u);
    if (old == GRID - 1) {
      __threadfence();
      double v = atomicAdd(acc, 0.0);
      out[0] = (float)v;
    }
  }
}

extern "C" void kernel_launch(void* const* d_in, const int* in_sizes, int n_in,
                              void* d_out, int out_size, void* d_ws, size_t ws_size,
                              hipStream_t stream) {
  const float* s       = (const float*)d_in[0];
  const float* y       = (const float*)d_in[1];
  const int*   ks      = (const int*)d_in[2];
  const int*   ts      = (const int*)d_in[3];
  const float* means   = (const float*)d_in[4];
  const float* covs    = (const float*)d_in[5];
  const float* b_mu    = (const float*)d_in[6];
  const float* b_ls    = (const float*)d_in[7];
  const float* beta_mu = (const float*)d_in[8];
  const float* beta_ls = (const float*)d_in[9];
  float* out = (float*)d_out;

  char* ws = (char*)d_ws;
  double* acc           = (double*)ws;
  unsigned int* counter = (unsigned int*)(ws + 8);
  float* cpack          = (float*)(ws + 64);
  int* wt               = (int*)(ws + 1024);
  float* pisT           = (float*)(ws + 16384);

  prep_kernel<<<2 + (NK * NT) / 256, 256, 0, stream>>>(
      y, means, covs, b_mu, b_ls, beta_mu, beta_ls, wt, cpack, pisT, acc, counter);
  spike_kernel<<<GRID, 256, 0, stream>>>(
      s, ks, ts, wt, cpack, pisT, acc, counter, out);
}